// Round 9
// baseline (349.847 us; speedup 1.0000x reference)
//
#include <hip/hip_runtime.h>

// Problem constants (fixed by setup_inputs)
#define B_  2
#define CK_ 64
#define CV_ 512
#define H_  48
#define W_  48
#define M_  18432   // T*H*W
#define N_  2304    // H*W

#define SSPLIT 8
#define MSEG   (M_ / SSPLIT)   // 2304
#define VSTRIDE16 (CV_ * 16)   // elems per m16 block in vt = 8192

typedef __bf16 bf16x8 __attribute__((ext_vector_type(8)));
typedef float  f32x4  __attribute__((ext_vector_type(4)));
typedef float  f32x16 __attribute__((ext_vector_type(16)));
typedef unsigned int u32x4 __attribute__((ext_vector_type(4)));

// logit = (2*ab - |k|^2)/sqrt(64); exp2 domain:
// arg = ab*(2*log2e/8) - ksq*(log2e/8). Q pre-scaled by C2Q at bf16-cast,
// ksq pre-scaled by C_KSQ, stored as bf16 hi+lo pair.
#define C2Q   0.36067376f
#define C_KSQ 0.18033688f

__device__ inline f32x16 mfma32(bf16x8 a, bf16x8 b, f32x16 c) {
    return __builtin_amdgcn_mfma_f32_32x32x16_bf16(a, b, c, 0, 0, 0);
}

__device__ inline unsigned pack_bf16(float lo, float hi) {
    union { __bf16 h; unsigned short u; } a, b;
    a.h = (__bf16)lo; b.h = (__bf16)hi;
    return ((unsigned)b.u << 16) | a.u;
}

// ---------------------------------------------------------------------------
// prep_k: ktile[b][mt][ks][h][l][8] : elem = K[b][m=32mt+l][k=16ks+8h+i]
// (QK A-frag load = contiguous 1KB wave-load). ksq2 = packed bf16 {hi,lo}.
// ---------------------------------------------------------------------------
__global__ __launch_bounds__(256) void prep_k(const float* __restrict__ mk,
                                              __bf16* __restrict__ ktile,
                                              unsigned* __restrict__ ksq2) {
    const int idx = blockIdx.x * 256 + threadIdx.x;   // B*M threads
    const int b = idx / M_, m = idx % M_;
    const float* src = mk + (size_t)b * CK_ * M_ + m;
    const int mt = m >> 5, l = m & 31;
    __bf16* dstb = ktile + (size_t)b * M_ * 64 + (size_t)mt * 2048 + l * 8;
    float s = 0.f;
#pragma unroll
    for (int j = 0; j < 8; ++j) {          // octet j: ks = j>>1, h = j&1
        bf16x8 o;
#pragma unroll
        for (int i = 0; i < 8; ++i) {
            float v = src[(size_t)(8 * j + i) * M_];
            s += v * v;
            o[i] = (__bf16)v;
        }
        *(bf16x8*)(dstb + (size_t)j * 256) = o;
    }
    const float tot = s * C_KSQ;
    const float hi = (float)(__bf16)tot;
    const float lo = tot - hi;
    ksq2[idx] = pack_bf16(hi, lo);
}

// ---------------------------------------------------------------------------
// prep_v: vt[b][m16][c][16] : elem = V[b][c][m=16*m16+i].
// ---------------------------------------------------------------------------
__global__ __launch_bounds__(256) void prep_v(const float* __restrict__ mv,
                                              __bf16* __restrict__ vt) {
    const int idx = blockIdx.x * 256 + threadIdx.x;   // B*1152*CV threads
    const int c   = idx % CV_;
    const int r   = idx / CV_;
    const int m16 = r % (M_ / 16);
    const int b   = r / (M_ / 16);
    const float4* s4 = (const float4*)(mv + ((size_t)b * CV_ + c) * M_ + m16 * 16);
    const float4 a0 = s4[0], a1 = s4[1], a2 = s4[2], a3 = s4[3];
    bf16x8 o0, o1;
    o0[0]=(__bf16)a0.x; o0[1]=(__bf16)a0.y; o0[2]=(__bf16)a0.z; o0[3]=(__bf16)a0.w;
    o0[4]=(__bf16)a1.x; o0[5]=(__bf16)a1.y; o0[6]=(__bf16)a1.z; o0[7]=(__bf16)a1.w;
    o1[0]=(__bf16)a2.x; o1[1]=(__bf16)a2.y; o1[2]=(__bf16)a2.z; o1[3]=(__bf16)a2.w;
    o1[4]=(__bf16)a3.x; o1[5]=(__bf16)a3.y; o1[6]=(__bf16)a3.z; o1[7]=(__bf16)a3.w;
    __bf16* dst = vt + ((size_t)r * CV_ + c) * 16;
    *(bf16x8*)dst = o0;
    *(bf16x8*)(dst + 8) = o1;
}

// ---------------------------------------------------------------------------
// flash7: F=2 (32 q x 256 c x M/8 per wave) tuned to fit 2 waves/SIMD.
// V staging cut 64->48 regs: va[8] (ks0 all ct) + vb[4] (ks1 ct0-3); ks1
// ct4-7 reloads va[0..3] after PV-ks0 consumes them. K one strip ahead.
// __launch_bounds__(256,2) pins the allocator at <=256 unified regs.
// Math/layout identical to rounds 5-8 (verified absmax 0.0156).
// ---------------------------------------------------------------------------

#define LOADK(kp_, kqp_, k0, k1, k2, k3, kq) do {                             \
    k0 = *(const bf16x8*)((kp_) + koff);                                      \
    k1 = *(const bf16x8*)((kp_) + koff + 512);                                \
    k2 = *(const bf16x8*)((kp_) + koff + 1024);                               \
    k3 = *(const bf16x8*)((kp_) + koff + 1536);                               \
    kq = (kqp_)[l31];                                                         \
} while (0)

// body: uses kc*, prefetches K(next strip) into kn*.
#define BODY(kc0, kc1, kc2, kc3, kqc, kn0, kn1, kn2, kn3, kqn, PREFK) do {    \
    /* V ks0 (8) + V ks1 first half (4) issued before compute */             \
    _Pragma("unroll")                                                         \
    for (int ct = 0; ct < 8; ++ct)                                            \
        va[ct] = *(const bf16x8*)(vp + voff + ct * 512);                      \
    _Pragma("unroll")                                                         \
    for (int j = 0; j < 4; ++j)                                               \
        vb[j] = *(const bf16x8*)(vp + VSTRIDE16 + voff + j * 512);            \
    if (PREFK) {                                                              \
        LOADK(kp, kqp, kn0, kn1, kn2, kn3, kqn);                              \
        kp += 2048; kqp += 32;                                                \
    }                                                                         \
    u32x4 _a4u = { h ? 0u : (kqc), 0u, 0u, 0u };                              \
    const bf16x8 _af4 = __builtin_bit_cast(bf16x8, _a4u);                     \
    f32x16 _d;                                                                \
    _Pragma("unroll") for (int r = 0; r < 16; ++r) _d[r] = 0.f;               \
    __builtin_amdgcn_s_setprio(1);                                            \
    _d = mfma32(_af4, bneg, _d);                                              \
    _d = mfma32(kc0, qf[0], _d);                                              \
    _d = mfma32(kc1, qf[1], _d);                                              \
    _d = mfma32(kc2, qf[2], _d);                                              \
    _d = mfma32(kc3, qf[3], _d);                                              \
    __builtin_amdgcn_s_setprio(0);                                            \
    unsigned _wpk[8];                                                         \
    _Pragma("unroll")                                                         \
    for (int j = 0; j < 8; ++j) {                                             \
        const float _pa = __builtin_amdgcn_exp2f(_d[2*j]);                    \
        const float _pc = __builtin_amdgcn_exp2f(_d[2*j+1]);                  \
        den[j & 3] += _pa + _pc;                                              \
        _wpk[j] = pack_bf16(_pa, _pc);                                        \
    }                                                                         \
    bf16x8 _pb0, _pb1;                                                        \
    {                                                                         \
        unsigned _a0 = _wpk[0], _b0 = _wpk[2];                                \
        unsigned _a1 = _wpk[1], _b1 = _wpk[3];                                \
        asm volatile("v_permlane32_swap_b32 %0, %1" : "+v"(_a0), "+v"(_b0));  \
        asm volatile("v_permlane32_swap_b32 %0, %1" : "+v"(_a1), "+v"(_b1));  \
        u32x4 _pu = {_a0, _a1, _b0, _b1};                                     \
        _pb0 = __builtin_bit_cast(bf16x8, _pu);                               \
    }                                                                         \
    {                                                                         \
        unsigned _a0 = _wpk[4], _b0 = _wpk[6];                                \
        unsigned _a1 = _wpk[5], _b1 = _wpk[7];                                \
        asm volatile("v_permlane32_swap_b32 %0, %1" : "+v"(_a0), "+v"(_b0));  \
        asm volatile("v_permlane32_swap_b32 %0, %1" : "+v"(_a1), "+v"(_b1));  \
        u32x4 _pu = {_a0, _a1, _b0, _b1};                                     \
        _pb1 = __builtin_bit_cast(bf16x8, _pu);                               \
    }                                                                         \
    __builtin_amdgcn_s_setprio(1);                                            \
    _Pragma("unroll")                                                         \
    for (int ct = 0; ct < 8; ++ct)                                            \
        acc[ct] = mfma32(va[ct], _pb0, acc[ct]);                              \
    __builtin_amdgcn_s_setprio(0);                                            \
    /* reload va[0..3] with V ks1 ct4-7 (old values dead) */                  \
    _Pragma("unroll")                                                         \
    for (int j = 0; j < 4; ++j)                                               \
        va[j] = *(const bf16x8*)(vp + VSTRIDE16 + voff + (4 + j) * 512);      \
    __builtin_amdgcn_s_setprio(1);                                            \
    _Pragma("unroll")                                                         \
    for (int j = 0; j < 4; ++j)                                               \
        acc[j] = mfma32(vb[j], _pb1, acc[j]);                                 \
    _Pragma("unroll")                                                         \
    for (int j = 0; j < 4; ++j)                                               \
        acc[4 + j] = mfma32(va[j], _pb1, acc[4 + j]);                         \
    __builtin_amdgcn_s_setprio(0);                                            \
} while (0)

__global__ __launch_bounds__(256, 2) void flash7_kernel(const __bf16* __restrict__ ktile,
                                                        const float* __restrict__ qk,
                                                        const __bf16* __restrict__ vt,
                                                        const unsigned* __restrict__ ksq2,
                                                        __bf16* __restrict__ partO,
                                                        float* __restrict__ partD) {
    const int tid = threadIdx.x;
    const int w = tid >> 6, lane = tid & 63;
    const int l31 = lane & 31, h = lane >> 5;

    // XCD-chunked decomposition: 32 groups (cs2,s,b) x 18 blocks; a group's
    // 72 waves share one K/V-segment stream -> one XCD's L2.
    const int bid = blockIdx.x;            // 0..575
    const int xcd = bid & 7;
    const int ixc = bid >> 3;              // 0..71
    const int grp = ixc / 18;              // 0..3
    const int blk = ixc % 18;              // 0..17
    const int G   = xcd * 4 + grp;         // 0..31
    const int cs2 = G & 1;
    const int sb  = G >> 1;                // 0..15
    const int s   = sb & 7, b = sb >> 3;
    const int nt  = blk * 4 + w;           // 0..71

    const int n0 = nt * 32;
    const int cw = cs2 * 256;
    const int m_base = s * MSEG;

    // lane-invariant load offsets (elements), computed ONCE
    const int koff = (h * 32 + l31) * 8;
    const int voff = (cw + l31) * 16 + 8 * h;

    // Q' B-frags: col = n0+l31, k = 16ks+8h+i, scaled by C2Q
    const float* qkb = qk + (size_t)b * CK_ * N_;
    bf16x8 qf[4];
#pragma unroll
    for (int ks = 0; ks < 4; ++ks)
#pragma unroll
      for (int i = 0; i < 8; ++i)
        qf[ks][i] = (__bf16)(qkb[(size_t)(16*ks + 8*h + i) * N_ + (n0 + l31)] * C2Q);

    // constant B-frag: -1.0bf16 at k slots {0,1}
    const u32x4 bneg_u = {0xBF80BF80u, 0u, 0u, 0u};
    const bf16x8 bneg = __builtin_bit_cast(bf16x8, bneg_u);

    // wave-uniform stream pointers, advanced by constant strides (SALU)
    const __bf16*   kp  = ktile + (size_t)b * M_ * 64 + (size_t)m_base * 64;
    const unsigned* kqp = ksq2  + (size_t)b * M_ + m_base;
    const __bf16*   vp  = vt    + (size_t)b * M_ * CV_ + (size_t)m_base * CV_;

    f32x16 acc[8];
#pragma unroll
    for (int ct = 0; ct < 8; ++ct)
#pragma unroll
      for (int r = 0; r < 16; ++r) acc[ct][r] = 0.f;
    float den[4] = {0.f, 0.f, 0.f, 0.f};

    bf16x8 kA0, kA1, kA2, kA3, kB0, kB1, kB2, kB3;
    unsigned kqA, kqB;
    bf16x8 va[8], vb[4];

    LOADK(kp, kqp, kA0, kA1, kA2, kA3, kqA);
    kp += 2048; kqp += 32;

    for (int mss = 0; mss < MSEG / 64 - 1; ++mss) {   // 35 double-bodies
        BODY(kA0, kA1, kA2, kA3, kqA, kB0, kB1, kB2, kB3, kqB, 1);
        vp += 2 * VSTRIDE16;
        BODY(kB0, kB1, kB2, kB3, kqB, kA0, kA1, kA2, kA3, kqA, 1);
        vp += 2 * VSTRIDE16;
    }
    // epilogue: strips 70 (A, prefetch 71 into B) and 71 (B, no prefetch)
    BODY(kA0, kA1, kA2, kA3, kqA, kB0, kB1, kB2, kB3, kqB, 1);
    vp += 2 * VSTRIDE16;
    BODY(kB0, kB1, kB2, kB3, kqB, kA0, kA1, kA2, kA3, kqA, 0);

    // denominator: lane holds sum over its 16 m-rows; add other half
    float dsum = (den[0] + den[1]) + (den[2] + den[3]);
    dsum += __shfl_xor(dsum, 32);
    if (cs2 == 0 && lane < 32)
        partD[(size_t)(s * B_ + b) * N_ + n0 + l31] = dsum;

    // unnormalized partial O in bf16: c = cw + 32ct + (r&3)+8*(r>>2)+4h
    __bf16* po = partO + (((size_t)(s * B_ + b) * CV_ + cw) * N_) + n0 + l31;
#pragma unroll
    for (int ct = 0; ct < 8; ++ct)
#pragma unroll
      for (int r = 0; r < 16; ++r) {
        const int crow = 32*ct + (r & 3) + 8*(r >> 2) + 4*h;
        po[(size_t)crow * N_] = (__bf16)acc[ct][r];
      }
}

// ---------------------------------------------------------------------------
// reduce: mem[b][c][n] = sum_s partO / sum_s partD  -> d_out channels 0..511
// ---------------------------------------------------------------------------
__global__ __launch_bounds__(256) void reduce_kernel(const __bf16* __restrict__ partO,
                                                     const float* __restrict__ partD,
                                                     float* __restrict__ out) {
    const int idx = blockIdx.x * 256 + threadIdx.x;   // B*CV*(N/8) threads
    const int n8 = idx % (N_ / 8);
    const int c  = (idx / (N_ / 8)) % CV_;
    const int b  = idx / ((N_ / 8) * CV_);
    float o[8] = {0,0,0,0,0,0,0,0};
    float dd[8] = {0,0,0,0,0,0,0,0};
#pragma unroll
    for (int s = 0; s < SSPLIT; ++s) {
        const bf16x8 ov = *(const bf16x8*)(partO + (((size_t)(s*B_+b)*CV_ + c) * N_) + n8*8);
        const float4 d0 = *(const float4*)(partD + (size_t)(s*B_+b)*N_ + n8*8);
        const float4 d1 = *(const float4*)(partD + (size_t)(s*B_+b)*N_ + n8*8 + 4);
#pragma unroll
        for (int j = 0; j < 8; ++j) o[j] += (float)ov[j];
        dd[0]+=d0.x; dd[1]+=d0.y; dd[2]+=d0.z; dd[3]+=d0.w;
        dd[4]+=d1.x; dd[5]+=d1.y; dd[6]+=d1.z; dd[7]+=d1.w;
    }
    float* op = out + ((size_t)b * (2*CV_) + c) * N_ + n8*8;
#pragma unroll
    for (int j = 0; j < 8; ++j) op[j] = o[j] / dd[j];
}

// ---------------------------------------------------------------------------
// conv_r: R_j[cc][b][p] = sum_{c in chunk cc} in[c][p] * w[c][j]
// ---------------------------------------------------------------------------
__global__ __launch_bounds__(256) void conv_r_kernel(const float* __restrict__ outf,
                                                     const float* __restrict__ qv,
                                                     const float* __restrict__ mask,
                                                     const float* __restrict__ cw,
                                                     float* __restrict__ Rp) {
    const int p  = blockIdx.x * 256 + threadIdx.x;   // 0..N-1
    const int cc = blockIdx.y;                        // 0..8
    const int b  = blockIdx.z;
    float r[9] = {0,0,0,0,0,0,0,0,0};
    if (cc < 8) {
        const float* src = (cc < 4) ? outf + ((size_t)b * (2*CV_) + cc * 128) * N_
                                    : qv   + ((size_t)b * CV_ + (cc - 4) * 128) * N_;
        const float* wb = cw + (size_t)cc * 128 * 9;
        for (int c = 0; c < 128; ++c) {
            const float v = src[(size_t)c * N_ + p];
#pragma unroll
            for (int j = 0; j < 9; ++j) r[j] += v * wb[c * 9 + j];
        }
    } else {
        const float v = mask[(size_t)b * N_ + p];
#pragma unroll
        for (int j = 0; j < 9; ++j) r[j] = v * cw[1024 * 9 + j];
    }
#pragma unroll
    for (int j = 0; j < 9; ++j)
        Rp[(((size_t)cc * 9 + j) * B_ + b) * N_ + p] = r[j];
}

// ---------------------------------------------------------------------------
// gate: gate[b][p] = sigmoid( sum_j sum_cc Rp[cc][j][b][neighbor_j(p)] + bias )
// ---------------------------------------------------------------------------
__global__ __launch_bounds__(256) void gate_kernel(const float* __restrict__ Rp,
                                                   const float* __restrict__ cbias,
                                                   float* __restrict__ gate_ws) {
    const int p = blockIdx.x * 256 + threadIdx.x;    // 0..N-1
    const int b = blockIdx.y;
    const int y = p / W_, x = p % W_;
    float sum = cbias[0];
#pragma unroll
    for (int dy = -1; dy <= 1; ++dy) {
        const int yy = y + dy;
        if (yy < 0 || yy >= H_) continue;
#pragma unroll
        for (int dx = -1; dx <= 1; ++dx) {
            const int xx = x + dx;
            if (xx < 0 || xx >= W_) continue;
            const int j = (dy + 1) * 3 + (dx + 1);
            const int q = yy * W_ + xx;
#pragma unroll
            for (int cc = 0; cc < 9; ++cc)
                sum += Rp[(((size_t)cc * 9 + j) * B_ + b) * N_ + q];
        }
    }
    gate_ws[(size_t)b * N_ + p] = 1.f / (1.f + __builtin_amdgcn_exp2f(-sum * 1.44269504f));
}

// ---------------------------------------------------------------------------
// finalize: out[b][ch][n] = (ch<512 ? mem : qv) * gate[b][n]
// ---------------------------------------------------------------------------
__global__ __launch_bounds__(256) void finalize_kernel(const float* __restrict__ qv,
                                                       const float* __restrict__ gate_ws,
                                                       float* __restrict__ out) {
    const int idx = blockIdx.x * 256 + threadIdx.x;
    const int n4 = N_ / 4;
    const int pos4 = idx % n4;
    const int row  = idx / n4;
    const int b = row >> 10, ch = row & 1023;
    const float4 gv = *(const float4*)(gate_ws + (size_t)b * N_ + pos4 * 4);
    float* op = out + (size_t)row * N_ + pos4 * 4;
    float4 v;
    if (ch < CV_) v = *(const float4*)op;
    else          v = *(const float4*)(qv + ((size_t)b * CV_ + (ch - CV_)) * N_ + pos4 * 4);
    v.x *= gv.x; v.y *= gv.y; v.z *= gv.z; v.w *= gv.w;
    *(float4*)op = v;
}

// ===========================================================================
extern "C" void kernel_launch(void* const* d_in, const int* in_sizes, int n_in,
                              void* d_out, int out_size, void* d_ws, size_t ws_size,
                              hipStream_t stream) {
    (void)in_sizes; (void)n_in; (void)out_size; (void)ws_size;
    const float* mk    = (const float*)d_in[0];
    const float* qk    = (const float*)d_in[1];
    const float* mv    = (const float*)d_in[2];
    const float* qv    = (const float*)d_in[3];
    const float* mask  = (const float*)d_in[4];
    const float* cw    = (const float*)d_in[5];
    const float* cbias = (const float*)d_in[6];
    float* outf = (float*)d_out;

    // workspace layout (bytes) — total 80,529,408, byte-identical to rounds 3-8
    const size_t kbf_b   = (size_t)B_ * M_ * 64 * 2;             //  4,718,592 (ktile; reused as Rp)
    const size_t vbf_b   = (size_t)B_ * CV_ * M_ * 2;            // 37,748,736 (vt)
    const size_t ksq_b   = (size_t)B_ * M_ * 4;                  //    147,456 (packed u32 hi/lo)
    const size_t partO_b = (size_t)SSPLIT * B_ * CV_ * N_ * 2;   // 37,748,736 (bf16)
    const size_t partD_b = (size_t)SSPLIT * B_ * N_ * 4;         //    147,456

    char* pw = (char*)d_ws;
    __bf16* ktile = (__bf16*)pw;
    float*  Rp    = (float*)pw;            // overlays ktile (dead after flash7)
    pw += kbf_b;
    __bf16* vt    = (__bf16*)pw;           pw += vbf_b;
    unsigned* ksq2 = (unsigned*)pw;        pw += ksq_b;
    __bf16* partO = (__bf16*)pw;           pw += partO_b;
    float*  partD = (float*)pw;            pw += partD_b;
    float*  gate_ws = (float*)pw;

    prep_k<<<dim3(B_ * M_ / 256), 256, 0, stream>>>(mk, ktile, ksq2);
    prep_v<<<dim3((size_t)B_ * (M_ / 16) * CV_ / 256, 1, 1), 256, 0, stream>>>(mv, vt);
    flash7_kernel<<<dim3(576), 256, 0, stream>>>(ktile, qk, vt, ksq2, partO, partD);
    reduce_kernel<<<dim3(B_ * CV_ * (N_ / 8) / 256), 256, 0, stream>>>(partO, partD, outf);
    conv_r_kernel<<<dim3(N_ / 256, 9, B_), 256, 0, stream>>>(outf, qv, mask, cw, Rp);
    gate_kernel<<<dim3(N_ / 256, B_), 256, 0, stream>>>(Rp, cbias, gate_ws);
    finalize_kernel<<<dim3((B_ * 2 * CV_ * N_ / 4) / 256), 256, 0, stream>>>(qv, gate_ws, outf);
}

// Round 10
// 251.699 us; speedup vs baseline: 1.3899x; 1.3899x over previous
//
#include <hip/hip_runtime.h>

// Problem constants (fixed by setup_inputs)
#define B_  2
#define CK_ 64
#define CV_ 512
#define H_  48
#define W_  48
#define M_  18432   // T*H*W
#define N_  2304    // H*W

#define SSPLIT 8
#define MSEG   (M_ / SSPLIT)   // 2304
#define VSTRIDE16 (CV_ * 16)   // elems per m16 block in vt = 8192

typedef __bf16 bf16x8 __attribute__((ext_vector_type(8)));
typedef float  f32x4  __attribute__((ext_vector_type(4)));
typedef float  f32x16 __attribute__((ext_vector_type(16)));
typedef unsigned int u32x4 __attribute__((ext_vector_type(4)));

// logit = (2*ab - |k|^2)/sqrt(64); exp2 domain:
// arg = ab*(2*log2e/8) - ksq*(log2e/8). Q pre-scaled by C2Q at bf16-cast,
// ksq pre-scaled by C_KSQ, stored as bf16 hi+lo pair.
#define C2Q   0.36067376f
#define C_KSQ 0.18033688f

__device__ inline f32x16 mfma32(bf16x8 a, bf16x8 b, f32x16 c) {
    return __builtin_amdgcn_mfma_f32_32x32x16_bf16(a, b, c, 0, 0, 0);
}

__device__ inline unsigned pack_bf16(float lo, float hi) {
    union { __bf16 h; unsigned short u; } a, b;
    a.h = (__bf16)lo; b.h = (__bf16)hi;
    return ((unsigned)b.u << 16) | a.u;
}

// ---------------------------------------------------------------------------
// prep_k: ktile[b][mt][ks][h][l][8] : elem = K[b][m=32mt+l][k=16ks+8h+i]
// (QK A-frag load = contiguous 1KB wave-load). ksq2 = packed bf16 {hi,lo}.
// ---------------------------------------------------------------------------
__global__ __launch_bounds__(256) void prep_k(const float* __restrict__ mk,
                                              __bf16* __restrict__ ktile,
                                              unsigned* __restrict__ ksq2) {
    const int idx = blockIdx.x * 256 + threadIdx.x;   // B*M threads
    const int b = idx / M_, m = idx % M_;
    const float* src = mk + (size_t)b * CK_ * M_ + m;
    const int mt = m >> 5, l = m & 31;
    __bf16* dstb = ktile + (size_t)b * M_ * 64 + (size_t)mt * 2048 + l * 8;
    float s = 0.f;
#pragma unroll
    for (int j = 0; j < 8; ++j) {          // octet j: ks = j>>1, h = j&1
        bf16x8 o;
#pragma unroll
        for (int i = 0; i < 8; ++i) {
            float v = src[(size_t)(8 * j + i) * M_];
            s += v * v;
            o[i] = (__bf16)v;
        }
        *(bf16x8*)(dstb + (size_t)j * 256) = o;
    }
    const float tot = s * C_KSQ;
    const float hi = (float)(__bf16)tot;
    const float lo = tot - hi;
    ksq2[idx] = pack_bf16(hi, lo);
}

// ---------------------------------------------------------------------------
// prep_v: vt[b][m16][c][16] : elem = V[b][c][m=16*m16+i].
// ---------------------------------------------------------------------------
__global__ __launch_bounds__(256) void prep_v(const float* __restrict__ mv,
                                              __bf16* __restrict__ vt) {
    const int idx = blockIdx.x * 256 + threadIdx.x;   // B*1152*CV threads
    const int c   = idx % CV_;
    const int r   = idx / CV_;
    const int m16 = r % (M_ / 16);
    const int b   = r / (M_ / 16);
    const float4* s4 = (const float4*)(mv + ((size_t)b * CV_ + c) * M_ + m16 * 16);
    const float4 a0 = s4[0], a1 = s4[1], a2 = s4[2], a3 = s4[3];
    bf16x8 o0, o1;
    o0[0]=(__bf16)a0.x; o0[1]=(__bf16)a0.y; o0[2]=(__bf16)a0.z; o0[3]=(__bf16)a0.w;
    o0[4]=(__bf16)a1.x; o0[5]=(__bf16)a1.y; o0[6]=(__bf16)a1.z; o0[7]=(__bf16)a1.w;
    o1[0]=(__bf16)a2.x; o1[1]=(__bf16)a2.y; o1[2]=(__bf16)a2.z; o1[3]=(__bf16)a2.w;
    o1[4]=(__bf16)a3.x; o1[5]=(__bf16)a3.y; o1[6]=(__bf16)a3.z; o1[7]=(__bf16)a3.w;
    __bf16* dst = vt + ((size_t)r * CV_ + c) * 16;
    *(bf16x8*)dst = o0;
    *(bf16x8*)(dst + 8) = o1;
}

// ---------------------------------------------------------------------------
// flash8: verified flash6 (F=2: 32 q x 256 c x M/8 per wave, 1 wave/SIMD)
// + V double-buffered ONE FULL STRIP ahead (vA/vB, 16 frags each). With
// ~340 peak regs out of the 512 available at 1 wave/SIMD there is no spill
// pressure (round-9 lesson: WRITE_SIZE is the spill canary).
// Math/layout identical to rounds 5-8 (verified absmax 0.0156).
// ---------------------------------------------------------------------------

#define LOADK(kp_, kqp_, k0, k1, k2, k3, kq) do {                             \
    k0 = *(const bf16x8*)((kp_) + koff);                                      \
    k1 = *(const bf16x8*)((kp_) + koff + 512);                                \
    k2 = *(const bf16x8*)((kp_) + koff + 1024);                               \
    k3 = *(const bf16x8*)((kp_) + koff + 1536);                               \
    kq = (kqp_)[l31];                                                         \
} while (0)

// fill a 16-frag V buffer from strip base pointer vb_
#define LOADV(vb_, vdst) do {                                                 \
    _Pragma("unroll")                                                         \
    for (int ct = 0; ct < 8; ++ct)                                            \
        vdst[ct] = *(const bf16x8*)((vb_) + voff + ct * 512);                 \
    _Pragma("unroll")                                                         \
    for (int ct = 0; ct < 8; ++ct)                                            \
        vdst[8 + ct] = *(const bf16x8*)((vb_) + VSTRIDE16 + voff + ct * 512); \
} while (0)

// body for strip s: consume vC/kc*, prefetch V(s+1) into vN and K(s+1) into kn*
#define BODY(vC, vN, kc0, kc1, kc2, kc3, kqc, kn0, kn1, kn2, kn3, kqn, PREFV, PREFK) do { \
    if (PREFV) LOADV(vp + 2 * VSTRIDE16, vN);                                 \
    if (PREFK) {                                                              \
        LOADK(kp, kqp, kn0, kn1, kn2, kn3, kqn);                              \
        kp += 2048; kqp += 32;                                                \
    }                                                                         \
    u32x4 _a4u = { h ? 0u : (kqc), 0u, 0u, 0u };                              \
    const bf16x8 _af4 = __builtin_bit_cast(bf16x8, _a4u);                     \
    f32x16 _d;                                                                \
    _Pragma("unroll") for (int r = 0; r < 16; ++r) _d[r] = 0.f;               \
    __builtin_amdgcn_s_setprio(1);                                            \
    _d = mfma32(_af4, bneg, _d);                                              \
    _d = mfma32(kc0, qf[0], _d);                                              \
    _d = mfma32(kc1, qf[1], _d);                                              \
    _d = mfma32(kc2, qf[2], _d);                                              \
    _d = mfma32(kc3, qf[3], _d);                                              \
    __builtin_amdgcn_s_setprio(0);                                            \
    unsigned _wpk[8];                                                         \
    _Pragma("unroll")                                                         \
    for (int j = 0; j < 8; ++j) {                                             \
        const float _pa = __builtin_amdgcn_exp2f(_d[2*j]);                    \
        const float _pc = __builtin_amdgcn_exp2f(_d[2*j+1]);                  \
        den[j & 3] += _pa + _pc;                                              \
        _wpk[j] = pack_bf16(_pa, _pc);                                        \
    }                                                                         \
    bf16x8 _pb0, _pb1;                                                        \
    {                                                                         \
        unsigned _a0 = _wpk[0], _b0 = _wpk[2];                                \
        unsigned _a1 = _wpk[1], _b1 = _wpk[3];                                \
        asm volatile("v_permlane32_swap_b32 %0, %1" : "+v"(_a0), "+v"(_b0));  \
        asm volatile("v_permlane32_swap_b32 %0, %1" : "+v"(_a1), "+v"(_b1));  \
        u32x4 _pu = {_a0, _a1, _b0, _b1};                                     \
        _pb0 = __builtin_bit_cast(bf16x8, _pu);                               \
    }                                                                         \
    {                                                                         \
        unsigned _a0 = _wpk[4], _b0 = _wpk[6];                                \
        unsigned _a1 = _wpk[5], _b1 = _wpk[7];                                \
        asm volatile("v_permlane32_swap_b32 %0, %1" : "+v"(_a0), "+v"(_b0));  \
        asm volatile("v_permlane32_swap_b32 %0, %1" : "+v"(_a1), "+v"(_b1));  \
        u32x4 _pu = {_a0, _a1, _b0, _b1};                                     \
        _pb1 = __builtin_bit_cast(bf16x8, _pu);                               \
    }                                                                         \
    __builtin_amdgcn_s_setprio(1);                                            \
    _Pragma("unroll")                                                         \
    for (int ct = 0; ct < 8; ++ct)                                            \
        acc[ct] = mfma32(vC[ct], _pb0, acc[ct]);                              \
    _Pragma("unroll")                                                         \
    for (int ct = 0; ct < 8; ++ct)                                            \
        acc[ct] = mfma32(vC[8 + ct], _pb1, acc[ct]);                          \
    __builtin_amdgcn_s_setprio(0);                                            \
    vp += 2 * VSTRIDE16;                                                      \
} while (0)

__global__ __launch_bounds__(256) void flash8_kernel(const __bf16* __restrict__ ktile,
                                                     const float* __restrict__ qk,
                                                     const __bf16* __restrict__ vt,
                                                     const unsigned* __restrict__ ksq2,
                                                     __bf16* __restrict__ partO,
                                                     float* __restrict__ partD) {
    const int tid = threadIdx.x;
    const int w = tid >> 6, lane = tid & 63;
    const int l31 = lane & 31, h = lane >> 5;

    // XCD-chunked decomposition: 32 groups (cs2,s,b) x 18 blocks; a group's
    // 72 waves share one K/V-segment stream -> one XCD's L2.
    const int bid = blockIdx.x;            // 0..575
    const int xcd = bid & 7;
    const int ixc = bid >> 3;              // 0..71
    const int grp = ixc / 18;              // 0..3
    const int blk = ixc % 18;              // 0..17
    const int G   = xcd * 4 + grp;         // 0..31
    const int cs2 = G & 1;
    const int sb  = G >> 1;                // 0..15
    const int s   = sb & 7, b = sb >> 3;
    const int nt  = blk * 4 + w;           // 0..71

    const int n0 = nt * 32;
    const int cw = cs2 * 256;
    const int m_base = s * MSEG;

    // lane-invariant load offsets (elements), computed ONCE
    const int koff = (h * 32 + l31) * 8;
    const int voff = (cw + l31) * 16 + 8 * h;

    // Q' B-frags: col = n0+l31, k = 16ks+8h+i, scaled by C2Q
    const float* qkb = qk + (size_t)b * CK_ * N_;
    bf16x8 qf[4];
#pragma unroll
    for (int ks = 0; ks < 4; ++ks)
#pragma unroll
      for (int i = 0; i < 8; ++i)
        qf[ks][i] = (__bf16)(qkb[(size_t)(16*ks + 8*h + i) * N_ + (n0 + l31)] * C2Q);

    // constant B-frag: -1.0bf16 at k slots {0,1}
    const u32x4 bneg_u = {0xBF80BF80u, 0u, 0u, 0u};
    const bf16x8 bneg = __builtin_bit_cast(bf16x8, bneg_u);

    // wave-uniform stream pointers, advanced by constant strides (SALU)
    const __bf16*   kp  = ktile + (size_t)b * M_ * 64 + (size_t)m_base * 64;
    const unsigned* kqp = ksq2  + (size_t)b * M_ + m_base;
    const __bf16*   vp  = vt    + (size_t)b * M_ * CV_ + (size_t)m_base * CV_;

    f32x16 acc[8];
#pragma unroll
    for (int ct = 0; ct < 8; ++ct)
#pragma unroll
      for (int r = 0; r < 16; ++r) acc[ct][r] = 0.f;
    float den[4] = {0.f, 0.f, 0.f, 0.f};

    bf16x8 kA0, kA1, kA2, kA3, kB0, kB1, kB2, kB3;
    unsigned kqA, kqB;
    bf16x8 vA[16], vB[16];

    // prologue: K(0) and V(0)
    LOADK(kp, kqp, kA0, kA1, kA2, kA3, kqA);
    kp += 2048; kqp += 32;
    LOADV(vp, vA);

    for (int mss = 0; mss < MSEG / 64 - 1; ++mss) {   // 35 double-bodies: strips 0..69
        BODY(vA, vB, kA0, kA1, kA2, kA3, kqA, kB0, kB1, kB2, kB3, kqB, 1, 1);
        BODY(vB, vA, kB0, kB1, kB2, kB3, kqB, kA0, kA1, kA2, kA3, kqA, 1, 1);
    }
    // strip 70: consume A, prefetch V(71)+K(71) into B
    BODY(vA, vB, kA0, kA1, kA2, kA3, kqA, kB0, kB1, kB2, kB3, kqB, 1, 1);
    // strip 71: consume B, no prefetch
    BODY(vB, vA, kB0, kB1, kB2, kB3, kqB, kA0, kA1, kA2, kA3, kqA, 0, 0);

    // denominator: lane holds sum over its 16 m-rows; add other half
    float dsum = (den[0] + den[1]) + (den[2] + den[3]);
    dsum += __shfl_xor(dsum, 32);
    if (cs2 == 0 && lane < 32)
        partD[(size_t)(s * B_ + b) * N_ + n0 + l31] = dsum;

    // unnormalized partial O in bf16: c = cw + 32ct + (r&3)+8*(r>>2)+4h
    __bf16* po = partO + (((size_t)(s * B_ + b) * CV_ + cw) * N_) + n0 + l31;
#pragma unroll
    for (int ct = 0; ct < 8; ++ct)
#pragma unroll
      for (int r = 0; r < 16; ++r) {
        const int crow = 32*ct + (r & 3) + 8*(r >> 2) + 4*h;
        po[(size_t)crow * N_] = (__bf16)acc[ct][r];
      }
}

// ---------------------------------------------------------------------------
// reduce: mem[b][c][n] = sum_s partO / sum_s partD  -> d_out channels 0..511
// ---------------------------------------------------------------------------
__global__ __launch_bounds__(256) void reduce_kernel(const __bf16* __restrict__ partO,
                                                     const float* __restrict__ partD,
                                                     float* __restrict__ out) {
    const int idx = blockIdx.x * 256 + threadIdx.x;   // B*CV*(N/8) threads
    const int n8 = idx % (N_ / 8);
    const int c  = (idx / (N_ / 8)) % CV_;
    const int b  = idx / ((N_ / 8) * CV_);
    float o[8] = {0,0,0,0,0,0,0,0};
    float dd[8] = {0,0,0,0,0,0,0,0};
#pragma unroll
    for (int s = 0; s < SSPLIT; ++s) {
        const bf16x8 ov = *(const bf16x8*)(partO + (((size_t)(s*B_+b)*CV_ + c) * N_) + n8*8);
        const float4 d0 = *(const float4*)(partD + (size_t)(s*B_+b)*N_ + n8*8);
        const float4 d1 = *(const float4*)(partD + (size_t)(s*B_+b)*N_ + n8*8 + 4);
#pragma unroll
        for (int j = 0; j < 8; ++j) o[j] += (float)ov[j];
        dd[0]+=d0.x; dd[1]+=d0.y; dd[2]+=d0.z; dd[3]+=d0.w;
        dd[4]+=d1.x; dd[5]+=d1.y; dd[6]+=d1.z; dd[7]+=d1.w;
    }
    float* op = out + ((size_t)b * (2*CV_) + c) * N_ + n8*8;
#pragma unroll
    for (int j = 0; j < 8; ++j) op[j] = o[j] / dd[j];
}

// ---------------------------------------------------------------------------
// conv_r: R_j[cc][b][p] = sum_{c in chunk cc} in[c][p] * w[c][j]
// ---------------------------------------------------------------------------
__global__ __launch_bounds__(256) void conv_r_kernel(const float* __restrict__ outf,
                                                     const float* __restrict__ qv,
                                                     const float* __restrict__ mask,
                                                     const float* __restrict__ cw,
                                                     float* __restrict__ Rp) {
    const int p  = blockIdx.x * 256 + threadIdx.x;   // 0..N-1
    const int cc = blockIdx.y;                        // 0..8
    const int b  = blockIdx.z;
    float r[9] = {0,0,0,0,0,0,0,0,0};
    if (cc < 8) {
        const float* src = (cc < 4) ? outf + ((size_t)b * (2*CV_) + cc * 128) * N_
                                    : qv   + ((size_t)b * CV_ + (cc - 4) * 128) * N_;
        const float* wb = cw + (size_t)cc * 128 * 9;
        for (int c = 0; c < 128; ++c) {
            const float v = src[(size_t)c * N_ + p];
#pragma unroll
            for (int j = 0; j < 9; ++j) r[j] += v * wb[c * 9 + j];
        }
    } else {
        const float v = mask[(size_t)b * N_ + p];
#pragma unroll
        for (int j = 0; j < 9; ++j) r[j] = v * cw[1024 * 9 + j];
    }
#pragma unroll
    for (int j = 0; j < 9; ++j)
        Rp[(((size_t)cc * 9 + j) * B_ + b) * N_ + p] = r[j];
}

// ---------------------------------------------------------------------------
// gate: gate[b][p] = sigmoid( sum_j sum_cc Rp[cc][j][b][neighbor_j(p)] + bias )
// ---------------------------------------------------------------------------
__global__ __launch_bounds__(256) void gate_kernel(const float* __restrict__ Rp,
                                                   const float* __restrict__ cbias,
                                                   float* __restrict__ gate_ws) {
    const int p = blockIdx.x * 256 + threadIdx.x;    // 0..N-1
    const int b = blockIdx.y;
    const int y = p / W_, x = p % W_;
    float sum = cbias[0];
#pragma unroll
    for (int dy = -1; dy <= 1; ++dy) {
        const int yy = y + dy;
        if (yy < 0 || yy >= H_) continue;
#pragma unroll
        for (int dx = -1; dx <= 1; ++dx) {
            const int xx = x + dx;
            if (xx < 0 || xx >= W_) continue;
            const int j = (dy + 1) * 3 + (dx + 1);
            const int q = yy * W_ + xx;
#pragma unroll
            for (int cc = 0; cc < 9; ++cc)
                sum += Rp[(((size_t)cc * 9 + j) * B_ + b) * N_ + q];
        }
    }
    gate_ws[(size_t)b * N_ + p] = 1.f / (1.f + __builtin_amdgcn_exp2f(-sum * 1.44269504f));
}

// ---------------------------------------------------------------------------
// finalize: out[b][ch][n] = (ch<512 ? mem : qv) * gate[b][n]
// ---------------------------------------------------------------------------
__global__ __launch_bounds__(256) void finalize_kernel(const float* __restrict__ qv,
                                                       const float* __restrict__ gate_ws,
                                                       float* __restrict__ out) {
    const int idx = blockIdx.x * 256 + threadIdx.x;
    const int n4 = N_ / 4;
    const int pos4 = idx % n4;
    const int row  = idx / n4;
    const int b = row >> 10, ch = row & 1023;
    const float4 gv = *(const float4*)(gate_ws + (size_t)b * N_ + pos4 * 4);
    float* op = out + (size_t)row * N_ + pos4 * 4;
    float4 v;
    if (ch < CV_) v = *(const float4*)op;
    else          v = *(const float4*)(qv + ((size_t)b * CV_ + (ch - CV_)) * N_ + pos4 * 4);
    v.x *= gv.x; v.y *= gv.y; v.z *= gv.z; v.w *= gv.w;
    *(float4*)op = v;
}

// ===========================================================================
extern "C" void kernel_launch(void* const* d_in, const int* in_sizes, int n_in,
                              void* d_out, int out_size, void* d_ws, size_t ws_size,
                              hipStream_t stream) {
    (void)in_sizes; (void)n_in; (void)out_size; (void)ws_size;
    const float* mk    = (const float*)d_in[0];
    const float* qk    = (const float*)d_in[1];
    const float* mv    = (const float*)d_in[2];
    const float* qv    = (const float*)d_in[3];
    const float* mask  = (const float*)d_in[4];
    const float* cw    = (const float*)d_in[5];
    const float* cbias = (const float*)d_in[6];
    float* outf = (float*)d_out;

    // workspace layout (bytes) — total 80,529,408, byte-identical to rounds 3-9
    const size_t kbf_b   = (size_t)B_ * M_ * 64 * 2;             //  4,718,592 (ktile; reused as Rp)
    const size_t vbf_b   = (size_t)B_ * CV_ * M_ * 2;            // 37,748,736 (vt)
    const size_t ksq_b   = (size_t)B_ * M_ * 4;                  //    147,456 (packed u32 hi/lo)
    const size_t partO_b = (size_t)SSPLIT * B_ * CV_ * N_ * 2;   // 37,748,736 (bf16)
    const size_t partD_b = (size_t)SSPLIT * B_ * N_ * 4;         //    147,456

    char* pw = (char*)d_ws;
    __bf16* ktile = (__bf16*)pw;
    float*  Rp    = (float*)pw;            // overlays ktile (dead after flash8)
    pw += kbf_b;
    __bf16* vt    = (__bf16*)pw;           pw += vbf_b;
    unsigned* ksq2 = (unsigned*)pw;        pw += ksq_b;
    __bf16* partO = (__bf16*)pw;           pw += partO_b;
    float*  partD = (float*)pw;            pw += partD_b;
    float*  gate_ws = (float*)pw;

    prep_k<<<dim3(B_ * M_ / 256), 256, 0, stream>>>(mk, ktile, ksq2);
    prep_v<<<dim3((size_t)B_ * (M_ / 16) * CV_ / 256, 1, 1), 256, 0, stream>>>(mv, vt);
    flash8_kernel<<<dim3(576), 256, 0, stream>>>(ktile, qk, vt, ksq2, partO, partD);
    reduce_kernel<<<dim3(B_ * CV_ * (N_ / 8) / 256), 256, 0, stream>>>(partO, partD, outf);
    conv_r_kernel<<<dim3(N_ / 256, 9, B_), 256, 0, stream>>>(outf, qv, mask, cw, Rp);
    gate_kernel<<<dim3(N_ / 256, B_), 256, 0, stream>>>(Rp, cbias, gate_ws);
    finalize_kernel<<<dim3((B_ * 2 * CV_ * N_ / 4) / 256), 256, 0, stream>>>(qv, gate_ws, outf);
}

// Round 11
// 243.136 us; speedup vs baseline: 1.4389x; 1.0352x over previous
//
#include <hip/hip_runtime.h>

// Problem constants (fixed by setup_inputs)
#define B_  2
#define CK_ 64
#define CV_ 512
#define H_  48
#define W_  48
#define M_  18432   // T*H*W
#define N_  2304    // H*W

#define SSPLIT 8
#define MSEG   (M_ / SSPLIT)   // 2304
#define VSTRIDE16 (CV_ * 16)   // elems per m16 block in vt = 8192

typedef __bf16 bf16x8 __attribute__((ext_vector_type(8)));
typedef float  f32x4  __attribute__((ext_vector_type(4)));
typedef float  f32x16 __attribute__((ext_vector_type(16)));
typedef unsigned int u32x4 __attribute__((ext_vector_type(4)));

// logit = (2*ab - |k|^2)/sqrt(64); exp2 domain:
// arg = ab*(2*log2e/8) - ksq*(log2e/8). Q pre-scaled by C2Q at bf16-cast,
// ksq pre-scaled by C_KSQ, stored as bf16 hi+lo pair.
#define C2Q   0.36067376f
#define C_KSQ 0.18033688f

__device__ inline f32x16 mfma32(bf16x8 a, bf16x8 b, f32x16 c) {
    return __builtin_amdgcn_mfma_f32_32x32x16_bf16(a, b, c, 0, 0, 0);
}

__device__ inline unsigned pack_bf16(float lo, float hi) {
    union { __bf16 h; unsigned short u; } a, b;
    a.h = (__bf16)lo; b.h = (__bf16)hi;
    return ((unsigned)b.u << 16) | a.u;
}

// ---------------------------------------------------------------------------
// prep_k: ktile[b][mt][ks][h][l][8] : elem = K[b][m=32mt+l][k=16ks+8h+i]
// (QK A-frag load = contiguous 1KB wave-load). ksq2 = packed bf16 {hi,lo}.
// ---------------------------------------------------------------------------
__global__ __launch_bounds__(256) void prep_k(const float* __restrict__ mk,
                                              __bf16* __restrict__ ktile,
                                              unsigned* __restrict__ ksq2) {
    const int idx = blockIdx.x * 256 + threadIdx.x;   // B*M threads
    const int b = idx / M_, m = idx % M_;
    const float* src = mk + (size_t)b * CK_ * M_ + m;
    const int mt = m >> 5, l = m & 31;
    __bf16* dstb = ktile + (size_t)b * M_ * 64 + (size_t)mt * 2048 + l * 8;
    float s = 0.f;
#pragma unroll
    for (int j = 0; j < 8; ++j) {          // octet j: ks = j>>1, h = j&1
        bf16x8 o;
#pragma unroll
        for (int i = 0; i < 8; ++i) {
            float v = src[(size_t)(8 * j + i) * M_];
            s += v * v;
            o[i] = (__bf16)v;
        }
        *(bf16x8*)(dstb + (size_t)j * 256) = o;
    }
    const float tot = s * C_KSQ;
    const float hi = (float)(__bf16)tot;
    const float lo = tot - hi;
    ksq2[idx] = pack_bf16(hi, lo);
}

// ---------------------------------------------------------------------------
// prep_v: vt[b][m16][c][16] : elem = V[b][c][m=16*m16+i].
// ---------------------------------------------------------------------------
__global__ __launch_bounds__(256) void prep_v(const float* __restrict__ mv,
                                              __bf16* __restrict__ vt) {
    const int idx = blockIdx.x * 256 + threadIdx.x;   // B*1152*CV threads
    const int c   = idx % CV_;
    const int r   = idx / CV_;
    const int m16 = r % (M_ / 16);
    const int b   = r / (M_ / 16);
    const float4* s4 = (const float4*)(mv + ((size_t)b * CV_ + c) * M_ + m16 * 16);
    const float4 a0 = s4[0], a1 = s4[1], a2 = s4[2], a3 = s4[3];
    bf16x8 o0, o1;
    o0[0]=(__bf16)a0.x; o0[1]=(__bf16)a0.y; o0[2]=(__bf16)a0.z; o0[3]=(__bf16)a0.w;
    o0[4]=(__bf16)a1.x; o0[5]=(__bf16)a1.y; o0[6]=(__bf16)a1.z; o0[7]=(__bf16)a1.w;
    o1[0]=(__bf16)a2.x; o1[1]=(__bf16)a2.y; o1[2]=(__bf16)a2.z; o1[3]=(__bf16)a2.w;
    o1[4]=(__bf16)a3.x; o1[5]=(__bf16)a3.y; o1[6]=(__bf16)a3.z; o1[7]=(__bf16)a3.w;
    __bf16* dst = vt + ((size_t)r * CV_ + c) * 16;
    *(bf16x8*)dst = o0;
    *(bf16x8*)(dst + 8) = o1;
}

// ---------------------------------------------------------------------------
// flash9: round-10 flash8 + explicit 2-stage in-wave pipeline.
// Per body (strip s): prefetch V(s+1)/K(s+2); QK(s+1) -> dN (K(s+1) arrived
// one strip ago); softmax(s) from dC (computed LAST body); PV(s) with V(s).
// The QK dep-chain of s+1 overlaps softmax/PV of s. Static A/B register
// naming throughout (no runtime indexing). ~370 peak unified regs at
// 1 wave/SIMD (512 budget) -> no spill (WRITE_SIZE is the canary).
// Math/layout identical to rounds 5-10 (verified absmax 0.0156).
// ---------------------------------------------------------------------------

#define LOADK(k0, k1, k2, k3, kq) do {                                        \
    k0 = *(const bf16x8*)(kp + koff);                                         \
    k1 = *(const bf16x8*)(kp + koff + 512);                                   \
    k2 = *(const bf16x8*)(kp + koff + 1024);                                  \
    k3 = *(const bf16x8*)(kp + koff + 1536);                                  \
    kq = kqp[l31];                                                            \
    kp += 2048; kqp += 32;                                                    \
} while (0)

#define LOADV(vb_, vdst) do {                                                 \
    _Pragma("unroll")                                                         \
    for (int ct = 0; ct < 8; ++ct)                                            \
        vdst[ct] = *(const bf16x8*)((vb_) + voff + ct * 512);                 \
    _Pragma("unroll")                                                         \
    for (int ct = 0; ct < 8; ++ct)                                            \
        vdst[8 + ct] = *(const bf16x8*)((vb_) + VSTRIDE16 + voff + ct * 512); \
} while (0)

// QK for one strip: dD = C2Q*ab - ksq (exp2-arg)
#define QKC(dD, k0, k1, k2, k3, kq) do {                                      \
    u32x4 _a4u = { h ? 0u : (kq), 0u, 0u, 0u };                               \
    const bf16x8 _af4 = __builtin_bit_cast(bf16x8, _a4u);                     \
    _Pragma("unroll") for (int r = 0; r < 16; ++r) dD[r] = 0.f;               \
    __builtin_amdgcn_s_setprio(1);                                            \
    dD = mfma32(_af4, bneg, dD);                                              \
    dD = mfma32(k0, qf[0], dD);                                               \
    dD = mfma32(k1, qf[1], dD);                                               \
    dD = mfma32(k2, qf[2], dD);                                               \
    dD = mfma32(k3, qf[3], dD);                                               \
    __builtin_amdgcn_s_setprio(0);                                            \
} while (0)

// body for strip s: dC = exp2-args(s) [from last body], vC = V(s);
// kc* = K(s+1) regs (for QK(s+1) -> dN), kn* = dest for K(s+2).
#define BODY(dC, dN, vC, vN, kc0, kc1, kc2, kc3, kqc,                         \
             kn0, kn1, kn2, kn3, kqn, PREFV, PREFK, PREFQK) do {              \
    if (PREFV) LOADV(vp + 2 * VSTRIDE16, vN);                                 \
    if (PREFK) LOADK(kn0, kn1, kn2, kn3, kqn);                                \
    if (PREFQK) QKC(dN, kc0, kc1, kc2, kc3, kqc);                             \
    unsigned _wpk[8];                                                         \
    _Pragma("unroll")                                                         \
    for (int j = 0; j < 8; ++j) {                                             \
        const float _pa = __builtin_amdgcn_exp2f(dC[2*j]);                    \
        const float _pc = __builtin_amdgcn_exp2f(dC[2*j+1]);                  \
        den[j & 3] += _pa + _pc;                                              \
        _wpk[j] = pack_bf16(_pa, _pc);                                        \
    }                                                                         \
    bf16x8 _pb0, _pb1;                                                        \
    {                                                                         \
        unsigned _a0 = _wpk[0], _b0 = _wpk[2];                                \
        unsigned _a1 = _wpk[1], _b1 = _wpk[3];                                \
        asm volatile("v_permlane32_swap_b32 %0, %1" : "+v"(_a0), "+v"(_b0));  \
        asm volatile("v_permlane32_swap_b32 %0, %1" : "+v"(_a1), "+v"(_b1));  \
        u32x4 _pu = {_a0, _a1, _b0, _b1};                                     \
        _pb0 = __builtin_bit_cast(bf16x8, _pu);                               \
    }                                                                         \
    {                                                                         \
        unsigned _a0 = _wpk[4], _b0 = _wpk[6];                                \
        unsigned _a1 = _wpk[5], _b1 = _wpk[7];                                \
        asm volatile("v_permlane32_swap_b32 %0, %1" : "+v"(_a0), "+v"(_b0));  \
        asm volatile("v_permlane32_swap_b32 %0, %1" : "+v"(_a1), "+v"(_b1));  \
        u32x4 _pu = {_a0, _a1, _b0, _b1};                                     \
        _pb1 = __builtin_bit_cast(bf16x8, _pu);                               \
    }                                                                         \
    __builtin_amdgcn_s_setprio(1);                                            \
    _Pragma("unroll")                                                         \
    for (int ct = 0; ct < 8; ++ct)                                            \
        acc[ct] = mfma32(vC[ct], _pb0, acc[ct]);                              \
    _Pragma("unroll")                                                         \
    for (int ct = 0; ct < 8; ++ct)                                            \
        acc[ct] = mfma32(vC[8 + ct], _pb1, acc[ct]);                          \
    __builtin_amdgcn_s_setprio(0);                                            \
    vp += 2 * VSTRIDE16;                                                      \
} while (0)

__global__ __launch_bounds__(256) void flash9_kernel(const __bf16* __restrict__ ktile,
                                                     const float* __restrict__ qk,
                                                     const __bf16* __restrict__ vt,
                                                     const unsigned* __restrict__ ksq2,
                                                     __bf16* __restrict__ partO,
                                                     float* __restrict__ partD) {
    const int tid = threadIdx.x;
    const int w = tid >> 6, lane = tid & 63;
    const int l31 = lane & 31, h = lane >> 5;

    // XCD-chunked decomposition: 32 groups (cs2,s,b) x 18 blocks; a group's
    // 72 waves share one K/V-segment stream -> one XCD's L2.
    const int bid = blockIdx.x;            // 0..575
    const int xcd = bid & 7;
    const int ixc = bid >> 3;              // 0..71
    const int grp = ixc / 18;              // 0..3
    const int blk = ixc % 18;              // 0..17
    const int G   = xcd * 4 + grp;         // 0..31
    const int cs2 = G & 1;
    const int sb  = G >> 1;                // 0..15
    const int s   = sb & 7, b = sb >> 3;
    const int nt  = blk * 4 + w;           // 0..71

    const int n0 = nt * 32;
    const int cw = cs2 * 256;
    const int m_base = s * MSEG;

    // lane-invariant load offsets (elements), computed ONCE
    const int koff = (h * 32 + l31) * 8;
    const int voff = (cw + l31) * 16 + 8 * h;

    // Q' B-frags: col = n0+l31, k = 16ks+8h+i, scaled by C2Q
    const float* qkb = qk + (size_t)b * CK_ * N_;
    bf16x8 qf[4];
#pragma unroll
    for (int ks = 0; ks < 4; ++ks)
#pragma unroll
      for (int i = 0; i < 8; ++i)
        qf[ks][i] = (__bf16)(qkb[(size_t)(16*ks + 8*h + i) * N_ + (n0 + l31)] * C2Q);

    // constant B-frag: -1.0bf16 at k slots {0,1}
    const u32x4 bneg_u = {0xBF80BF80u, 0u, 0u, 0u};
    const bf16x8 bneg = __builtin_bit_cast(bf16x8, bneg_u);

    // wave-uniform stream pointers, advanced by constant strides (SALU)
    const __bf16*   kp  = ktile + (size_t)b * M_ * 64 + (size_t)m_base * 64;
    const unsigned* kqp = ksq2  + (size_t)b * M_ + m_base;
    const __bf16*   vp  = vt    + (size_t)b * M_ * CV_ + (size_t)m_base * CV_;

    f32x16 acc[8];
#pragma unroll
    for (int ct = 0; ct < 8; ++ct)
#pragma unroll
      for (int r = 0; r < 16; ++r) acc[ct][r] = 0.f;
    float den[4] = {0.f, 0.f, 0.f, 0.f};

    bf16x8 kA0, kA1, kA2, kA3, kB0, kB1, kB2, kB3;
    unsigned kqA, kqB;
    bf16x8 vA[16], vB[16];
    f32x16 dA, dB;

    // prologue: K(0)->kA, V(0)->vA, K(1)->kB, d(0)=QK(kA)
    LOADK(kA0, kA1, kA2, kA3, kqA);
    LOADV(vp, vA);
    LOADK(kB0, kB1, kB2, kB3, kqB);
    QKC(dA, kA0, kA1, kA2, kA3, kqA);

    for (int mss = 0; mss < MSEG / 64 - 1; ++mss) {   // strips 0..69
        // even strip s: consume dA/vA; QK(s+1) from kB -> dB; K(s+2) -> kA
        BODY(dA, dB, vA, vB, kB0, kB1, kB2, kB3, kqB,
             kA0, kA1, kA2, kA3, kqA, 1, 1, 1);
        // odd strip s+1: consume dB/vB; QK(s+2) from kA -> dA; K(s+3) -> kB
        BODY(dB, dA, vB, vA, kA0, kA1, kA2, kA3, kqA,
             kB0, kB1, kB2, kB3, kqB, 1, 1, 1);
    }
    // strip 70: V(71) -> vB, no K prefetch, QK(71) from kB -> dB
    BODY(dA, dB, vA, vB, kB0, kB1, kB2, kB3, kqB,
         kA0, kA1, kA2, kA3, kqA, 1, 0, 1);
    // strip 71: consume dB/vB, nothing prefetched
    BODY(dB, dA, vB, vA, kA0, kA1, kA2, kA3, kqA,
         kB0, kB1, kB2, kB3, kqB, 0, 0, 0);

    // denominator: lane holds sum over its 16 m-rows; add other half
    float dsum = (den[0] + den[1]) + (den[2] + den[3]);
    dsum += __shfl_xor(dsum, 32);
    if (cs2 == 0 && lane < 32)
        partD[(size_t)(s * B_ + b) * N_ + n0 + l31] = dsum;

    // unnormalized partial O in bf16: c = cw + 32ct + (r&3)+8*(r>>2)+4h
    __bf16* po = partO + (((size_t)(s * B_ + b) * CV_ + cw) * N_) + n0 + l31;
#pragma unroll
    for (int ct = 0; ct < 8; ++ct)
#pragma unroll
      for (int r = 0; r < 16; ++r) {
        const int crow = 32*ct + (r & 3) + 8*(r >> 2) + 4*h;
        po[(size_t)crow * N_] = (__bf16)acc[ct][r];
      }
}

// ---------------------------------------------------------------------------
// reduce: mem[b][c][n] = sum_s partO / sum_s partD  -> d_out channels 0..511
// ---------------------------------------------------------------------------
__global__ __launch_bounds__(256) void reduce_kernel(const __bf16* __restrict__ partO,
                                                     const float* __restrict__ partD,
                                                     float* __restrict__ out) {
    const int idx = blockIdx.x * 256 + threadIdx.x;   // B*CV*(N/8) threads
    const int n8 = idx % (N_ / 8);
    const int c  = (idx / (N_ / 8)) % CV_;
    const int b  = idx / ((N_ / 8) * CV_);
    float o[8] = {0,0,0,0,0,0,0,0};
    float dd[8] = {0,0,0,0,0,0,0,0};
#pragma unroll
    for (int s = 0; s < SSPLIT; ++s) {
        const bf16x8 ov = *(const bf16x8*)(partO + (((size_t)(s*B_+b)*CV_ + c) * N_) + n8*8);
        const float4 d0 = *(const float4*)(partD + (size_t)(s*B_+b)*N_ + n8*8);
        const float4 d1 = *(const float4*)(partD + (size_t)(s*B_+b)*N_ + n8*8 + 4);
#pragma unroll
        for (int j = 0; j < 8; ++j) o[j] += (float)ov[j];
        dd[0]+=d0.x; dd[1]+=d0.y; dd[2]+=d0.z; dd[3]+=d0.w;
        dd[4]+=d1.x; dd[5]+=d1.y; dd[6]+=d1.z; dd[7]+=d1.w;
    }
    float* op = out + ((size_t)b * (2*CV_) + c) * N_ + n8*8;
#pragma unroll
    for (int j = 0; j < 8; ++j) op[j] = o[j] / dd[j];
}

// ---------------------------------------------------------------------------
// conv_r: R_j[cc][b][p] = sum_{c in chunk cc} in[c][p] * w[c][j]
// ---------------------------------------------------------------------------
__global__ __launch_bounds__(256) void conv_r_kernel(const float* __restrict__ outf,
                                                     const float* __restrict__ qv,
                                                     const float* __restrict__ mask,
                                                     const float* __restrict__ cw,
                                                     float* __restrict__ Rp) {
    const int p  = blockIdx.x * 256 + threadIdx.x;   // 0..N-1
    const int cc = blockIdx.y;                        // 0..8
    const int b  = blockIdx.z;
    float r[9] = {0,0,0,0,0,0,0,0,0};
    if (cc < 8) {
        const float* src = (cc < 4) ? outf + ((size_t)b * (2*CV_) + cc * 128) * N_
                                    : qv   + ((size_t)b * CV_ + (cc - 4) * 128) * N_;
        const float* wb = cw + (size_t)cc * 128 * 9;
        for (int c = 0; c < 128; ++c) {
            const float v = src[(size_t)c * N_ + p];
#pragma unroll
            for (int j = 0; j < 9; ++j) r[j] += v * wb[c * 9 + j];
        }
    } else {
        const float v = mask[(size_t)b * N_ + p];
#pragma unroll
        for (int j = 0; j < 9; ++j) r[j] = v * cw[1024 * 9 + j];
    }
#pragma unroll
    for (int j = 0; j < 9; ++j)
        Rp[(((size_t)cc * 9 + j) * B_ + b) * N_ + p] = r[j];
}

// ---------------------------------------------------------------------------
// gate: gate[b][p] = sigmoid( sum_j sum_cc Rp[cc][j][b][neighbor_j(p)] + bias )
// ---------------------------------------------------------------------------
__global__ __launch_bounds__(256) void gate_kernel(const float* __restrict__ Rp,
                                                   const float* __restrict__ cbias,
                                                   float* __restrict__ gate_ws) {
    const int p = blockIdx.x * 256 + threadIdx.x;    // 0..N-1
    const int b = blockIdx.y;
    const int y = p / W_, x = p % W_;
    float sum = cbias[0];
#pragma unroll
    for (int dy = -1; dy <= 1; ++dy) {
        const int yy = y + dy;
        if (yy < 0 || yy >= H_) continue;
#pragma unroll
        for (int dx = -1; dx <= 1; ++dx) {
            const int xx = x + dx;
            if (xx < 0 || xx >= W_) continue;
            const int j = (dy + 1) * 3 + (dx + 1);
            const int q = yy * W_ + xx;
#pragma unroll
            for (int cc = 0; cc < 9; ++cc)
                sum += Rp[(((size_t)cc * 9 + j) * B_ + b) * N_ + q];
        }
    }
    gate_ws[(size_t)b * N_ + p] = 1.f / (1.f + __builtin_amdgcn_exp2f(-sum * 1.44269504f));
}

// ---------------------------------------------------------------------------
// finalize: out[b][ch][n] = (ch<512 ? mem : qv) * gate[b][n]
// ---------------------------------------------------------------------------
__global__ __launch_bounds__(256) void finalize_kernel(const float* __restrict__ qv,
                                                       const float* __restrict__ gate_ws,
                                                       float* __restrict__ out) {
    const int idx = blockIdx.x * 256 + threadIdx.x;
    const int n4 = N_ / 4;
    const int pos4 = idx % n4;
    const int row  = idx / n4;
    const int b = row >> 10, ch = row & 1023;
    const float4 gv = *(const float4*)(gate_ws + (size_t)b * N_ + pos4 * 4);
    float* op = out + (size_t)row * N_ + pos4 * 4;
    float4 v;
    if (ch < CV_) v = *(const float4*)op;
    else          v = *(const float4*)(qv + ((size_t)b * CV_ + (ch - CV_)) * N_ + pos4 * 4);
    v.x *= gv.x; v.y *= gv.y; v.z *= gv.z; v.w *= gv.w;
    *(float4*)op = v;
}

// ===========================================================================
extern "C" void kernel_launch(void* const* d_in, const int* in_sizes, int n_in,
                              void* d_out, int out_size, void* d_ws, size_t ws_size,
                              hipStream_t stream) {
    (void)in_sizes; (void)n_in; (void)out_size; (void)ws_size;
    const float* mk    = (const float*)d_in[0];
    const float* qk    = (const float*)d_in[1];
    const float* mv    = (const float*)d_in[2];
    const float* qv    = (const float*)d_in[3];
    const float* mask  = (const float*)d_in[4];
    const float* cw    = (const float*)d_in[5];
    const float* cbias = (const float*)d_in[6];
    float* outf = (float*)d_out;

    // workspace layout (bytes) — total 80,529,408, byte-identical to rounds 3-10
    const size_t kbf_b   = (size_t)B_ * M_ * 64 * 2;             //  4,718,592 (ktile; reused as Rp)
    const size_t vbf_b   = (size_t)B_ * CV_ * M_ * 2;            // 37,748,736 (vt)
    const size_t ksq_b   = (size_t)B_ * M_ * 4;                  //    147,456 (packed u32 hi/lo)
    const size_t partO_b = (size_t)SSPLIT * B_ * CV_ * N_ * 2;   // 37,748,736 (bf16)
    const size_t partD_b = (size_t)SSPLIT * B_ * N_ * 4;         //    147,456

    char* pw = (char*)d_ws;
    __bf16* ktile = (__bf16*)pw;
    float*  Rp    = (float*)pw;            // overlays ktile (dead after flash9)
    pw += kbf_b;
    __bf16* vt    = (__bf16*)pw;           pw += vbf_b;
    unsigned* ksq2 = (unsigned*)pw;        pw += ksq_b;
    __bf16* partO = (__bf16*)pw;           pw += partO_b;
    float*  partD = (float*)pw;            pw += partD_b;
    float*  gate_ws = (float*)pw;

    prep_k<<<dim3(B_ * M_ / 256), 256, 0, stream>>>(mk, ktile, ksq2);
    prep_v<<<dim3((size_t)B_ * (M_ / 16) * CV_ / 256, 1, 1), 256, 0, stream>>>(mv, vt);
    flash9_kernel<<<dim3(576), 256, 0, stream>>>(ktile, qk, vt, ksq2, partO, partD);
    reduce_kernel<<<dim3(B_ * CV_ * (N_ / 8) / 256), 256, 0, stream>>>(partO, partD, outf);
    conv_r_kernel<<<dim3(N_ / 256, 9, B_), 256, 0, stream>>>(outf, qv, mask, cw, Rp);
    gate_kernel<<<dim3(N_ / 256, B_), 256, 0, stream>>>(Rp, cbias, gate_ws);
    finalize_kernel<<<dim3((B_ * 2 * CV_ * N_ / 4) / 256), 256, 0, stream>>>(qv, gate_ws, outf);
}